// Round 1
// baseline (1797.676 us; speedup 1.0000x reference)
//
#include <hip/hip_runtime.h>
#include <hip/hip_bf16.h>
#include <stdint.h>

#define DEV __device__ __forceinline__

typedef __bf16 bf16;
typedef __attribute__((ext_vector_type(8))) __bf16 bf16x8;
typedef __attribute__((ext_vector_type(4))) float f32x4;

constexpr int Bb = 128, Tt = 199, Ee = 256, Hh = 256;
constexpr int Mm = Bb * Tt;       // 25472 = 199 M-tiles of 128 exactly
constexpr int G4 = 4 * Hh;        // 1024 gates

// ---------------- workspace layout (bytes) ----------------
constexpr size_t OFF_FLAGS = 0;                                   // 64 flags @128B stride
constexpr size_t OFF_WLI_H = 8192;
constexpr size_t OFF_WLI_L = OFF_WLI_H + (size_t)Hh * 768 * 2;
constexpr size_t OFF_WIH_H = OFF_WLI_L + (size_t)Hh * 768 * 2;
constexpr size_t OFF_WIH_L = OFF_WIH_H + (size_t)G4 * Hh * 2;
constexpr size_t OFF_WNF_H = OFF_WIH_L + (size_t)G4 * Hh * 2;
constexpr size_t OFF_WNF_L = OFF_WNF_H + (size_t)Hh * Ee * 2;
constexpr size_t OFF_XIN_H = OFF_WNF_L + (size_t)Hh * Ee * 2;
constexpr size_t OFF_XIN_L = OFF_XIN_H + (size_t)Mm * Hh * 2;
constexpr size_t OFF_XP    = OFF_XIN_L + (size_t)Mm * Hh * 2;     // f32 [t][b][1024]
constexpr size_t OFF_HEX   = OFF_XP    + (size_t)Mm * G4 * 4;     // f32 [g][t][16][256]
constexpr size_t OFF_NTR   = OFF_HEX   + (size_t)Mm * Hh * 4;     // f32 [t*128+b][256]
constexpr size_t WS_NEED   = OFF_NTR   + (size_t)Mm * Hh * 4;     // ~176 MiB total

DEV float sigm(float x)  { return 1.0f / (1.0f + __expf(-x)); }
DEV float tanh_(float x) { return 2.0f / (1.0f + __expf(-2.0f * x)) - 1.0f; }

// ============================================================
// k_reset: zero the lstm sync flags (must run before k_lstm each call)
// ============================================================
__global__ void k_reset(unsigned int* flags) {
    int i = blockIdx.x * 256 + threadIdx.x;
    if (i < 64 * 32) flags[i] = 0;
}

// ============================================================
// k_prep: split weights into bf16 hi/lo pairs
// ============================================================
__global__ void k_prep(const float* __restrict__ Wli, const float* __restrict__ Wih,
                       const float* __restrict__ Wnf,
                       bf16* wli_h, bf16* wli_l, bf16* wih_h, bf16* wih_l,
                       bf16* wnf_h, bf16* wnf_l) {
    const int n1 = Hh * 768, n2 = G4 * Hh, n3 = Hh * Ee;
    for (int idx = blockIdx.x * 256 + threadIdx.x; idx < n1 + n2 + n3;
         idx += gridDim.x * 256) {
        const float* src; bf16 *dh, *dl; int j;
        if (idx < n1)           { src = Wli; dh = wli_h; dl = wli_l; j = idx; }
        else if (idx < n1 + n2) { src = Wih; dh = wih_h; dl = wih_l; j = idx - n1; }
        else                    { src = Wnf; dh = wnf_h; dl = wnf_l; j = idx - n1 - n2; }
        float x = src[j];
        bf16 h = (bf16)x;
        dh[j] = h;
        dl[j] = (bf16)(x - (float)h);
    }
}

// ============================================================
// k_gemm: split-bf16 (3-pass) 128x128x64-tile GEMM, 4 waves.
//   M index m = t*128 + b  (M=25472 = 199 tiles exactly, blockIdx.x = t)
//   AMODE: 0 = concat3 f32 (q|ans|skill), on-the-fly hi/lo split
//          1 = single f32 source, on-the-fly split
//          2 = pre-split bf16 pair
//   EPI:   0 = add bias0, store hi/lo bf16 pair
//          1 = add bias0+bias1, store f32
//          2 = add bias0, relu, store f32
// ============================================================
template<int AMODE, int EPI, int KT, int NTOT>
__global__ __launch_bounds__(256, 2)
void k_gemm(const float* __restrict__ a0, const float* __restrict__ a1,
            const float* __restrict__ a2,
            const bf16* __restrict__ ah_src, const bf16* __restrict__ al_src,
            const bf16* __restrict__ bh_src, const bf16* __restrict__ bl_src,
            const float* __restrict__ bias0, const float* __restrict__ bias1,
            float* __restrict__ outf, bf16* __restrict__ outh, bf16* __restrict__ outl)
{
    __shared__ __align__(16) bf16 lA[2][128 * 64];   // [hi/lo][row*64 + swz]
    __shared__ __align__(16) bf16 lB[2][128 * 64];
    const int tid = threadIdx.x;
    const int l = tid & 63, w = tid >> 6;
    const int wr = w >> 1, wc = w & 1;       // 2x2 wave grid, 64x64 per wave
    const int lr = l & 15, lh = l >> 4;
    const int mb = blockIdx.x;               // == t
    const int nb = blockIdx.y;

    f32x4 acc[4][4];
    #pragma unroll
    for (int i = 0; i < 4; ++i)
        #pragma unroll
        for (int j = 0; j < 4; ++j) acc[i][j] = {};

    for (int ks = 0; ks < KT / 64; ++ks) {
        // ---- stage A and B tiles (reg-staged, swizzled: granule ^ (row&7)) ----
        #pragma unroll
        for (int p = 0; p < 4; ++p) {
            int Gi = p * 256 + tid;            // 1024 granules of 8 elems
            int row = Gi >> 3, gsl = Gi & 7;
            int k = ks * 64 + gsl * 8;
            int dst = row * 64 + ((gsl ^ (row & 7)) * 8);
            // A
            if constexpr (AMODE == 2) {
                size_t base = (size_t)(mb * 128 + row) * KT + k;
                *(bf16x8*)&lA[0][dst] = *(const bf16x8*)(ah_src + base);
                *(bf16x8*)&lA[1][dst] = *(const bf16x8*)(al_src + base);
            } else {
                const float* src; int e;
                if constexpr (AMODE == 0) {
                    int seg = k >> 8; e = k & 255;
                    src = (seg == 0) ? a0 : (seg == 1) ? a1 : a2;
                } else { src = a0; e = k; }
                size_t base = ((size_t)row * Tt + mb) * Ee + e;  // [b][t][e]
                float4 v0 = *(const float4*)(src + base);
                float4 v1 = *(const float4*)(src + base + 4);
                float vv[8] = {v0.x, v0.y, v0.z, v0.w, v1.x, v1.y, v1.z, v1.w};
                bf16x8 hv, lv;
                #pragma unroll
                for (int j = 0; j < 8; ++j) {
                    bf16 h = (bf16)vv[j];
                    hv[j] = h;
                    lv[j] = (bf16)(vv[j] - (float)h);
                }
                *(bf16x8*)&lA[0][dst] = hv;
                *(bf16x8*)&lA[1][dst] = lv;
            }
            // B (weights, always pre-split)
            size_t bbase = (size_t)(nb * 128 + row) * KT + k;
            *(bf16x8*)&lB[0][dst] = *(const bf16x8*)(bh_src + bbase);
            *(bf16x8*)&lB[1][dst] = *(const bf16x8*)(bl_src + bbase);
        }
        __syncthreads();
        #pragma unroll
        for (int kt = 0; kt < 2; ++kt) {
            bf16x8 ah[4], al[4], bh[4], bl[4];
            #pragma unroll
            for (int mt = 0; mt < 4; ++mt) {
                int row = wr * 64 + mt * 16 + lr;
                int g = (kt * 4 + lh) ^ (row & 7);
                ah[mt] = *(const bf16x8*)&lA[0][row * 64 + g * 8];
                al[mt] = *(const bf16x8*)&lA[1][row * 64 + g * 8];
            }
            #pragma unroll
            for (int nt = 0; nt < 4; ++nt) {
                int row = wc * 64 + nt * 16 + lr;
                int g = (kt * 4 + lh) ^ (row & 7);
                bh[nt] = *(const bf16x8*)&lB[0][row * 64 + g * 8];
                bl[nt] = *(const bf16x8*)&lB[1][row * 64 + g * 8];
            }
            #pragma unroll
            for (int mt = 0; mt < 4; ++mt)
                #pragma unroll
                for (int nt = 0; nt < 4; ++nt) {
                    acc[mt][nt] = __builtin_amdgcn_mfma_f32_16x16x32_bf16(ah[mt], bh[nt], acc[mt][nt], 0, 0, 0);
                    acc[mt][nt] = __builtin_amdgcn_mfma_f32_16x16x32_bf16(ah[mt], bl[nt], acc[mt][nt], 0, 0, 0);
                    acc[mt][nt] = __builtin_amdgcn_mfma_f32_16x16x32_bf16(al[mt], bh[nt], acc[mt][nt], 0, 0, 0);
                }
        }
        __syncthreads();
    }
    // ---- epilogue: D layout col = l&15 (n), row = (l>>4)*4 + r (m) ----
    #pragma unroll
    for (int nt = 0; nt < 4; ++nt) {
        int n = nb * 128 + wc * 64 + nt * 16 + lr;
        float bv = bias0[n];
        if constexpr (EPI == 1) bv += bias1[n];
        #pragma unroll
        for (int mt = 0; mt < 4; ++mt)
            #pragma unroll
            for (int r = 0; r < 4; ++r) {
                int m = mb * 128 + wr * 64 + mt * 16 + lh * 4 + r;
                float v = acc[mt][nt][r] + bv;
                if constexpr (EPI == 0) {
                    bf16 h = (bf16)v;
                    outh[(size_t)m * NTOT + n] = h;
                    outl[(size_t)m * NTOT + n] = (bf16)(v - (float)h);
                } else if constexpr (EPI == 1) {
                    outf[(size_t)m * NTOT + n] = v;
                } else {
                    outf[(size_t)m * NTOT + n] = fmaxf(v, 0.f);
                }
            }
    }
}

// ============================================================
// k_lstm: 8 batch-groups x 8 participant WGs (grid=64, 256 thr = 4 waves).
// Participant c owns 32 hidden units -> 128 gate rows; W_hh fragments live
// in VGPRs. Per-step cross-WG sync via device-scope atomic flags; h exchanged
// through hexch (f32, agent-scope atomics). wave w: qsel=w&1 (0: i,f | 1: g,o),
// hsel=w>>1 (which 16-unit half).
// ============================================================
__global__ __launch_bounds__(256, 1)
void k_lstm(const float* __restrict__ Whh, const float* __restrict__ xp,
            float* __restrict__ hexch, unsigned int* __restrict__ flags)
{
    const int tid = threadIdx.x;
    const int l = tid & 63, w = tid >> 6;
    const int g = blockIdx.x >> 3, c = blockIdx.x & 7;
    const int qsel = w & 1, hsel = w >> 1;
    const int lr = l & 15, lh = l >> 4;
    const int bi = lh * 4;                      // local batch base for regs

    __shared__ float zone[2][2][64][4];         // [hsel][tau(g,o)][lane][reg]

    // ---- hoist W_hh fragments into VGPRs (B-operand: col = l&15 = gate row) ----
    bf16x8 wf[2][8];
    int n0[2];
    #pragma unroll
    for (int tau = 0; tau < 2; ++tau) {
        n0[tau] = (qsel * 2 + tau) * 256 + c * 32 + hsel * 16;
        #pragma unroll
        for (int kt = 0; kt < 8; ++kt) {
            size_t base = (size_t)(n0[tau] + lr) * Hh + kt * 32 + lh * 8;
            float4 v0 = *(const float4*)(Whh + base);
            float4 v1 = *(const float4*)(Whh + base + 4);
            float vv[8] = {v0.x, v0.y, v0.z, v0.w, v1.x, v1.y, v1.z, v1.w};
            #pragma unroll
            for (int j = 0; j < 8; ++j) wf[tau][kt][j] = (bf16)vv[j];
        }
    }

    float xc[2][4], xn[2][4];
    #pragma unroll
    for (int tau = 0; tau < 2; ++tau)
        #pragma unroll
        for (int r = 0; r < 4; ++r)
            xc[tau][r] = xp[((size_t)0 * Bb + g * 16 + bi + r) * G4 + n0[tau] + lr];

    float cst[4] = {0.f, 0.f, 0.f, 0.f};
    unsigned int* selfflag = flags + (g * 8 + c) * 32;

    for (int t = 0; t < Tt; ++t) {
        // prefetch xp for t+1 (independent of sync)
        int tn = (t + 1 < Tt) ? t + 1 : t;
        #pragma unroll
        for (int tau = 0; tau < 2; ++tau)
            #pragma unroll
            for (int r = 0; r < 4; ++r)
                xn[tau][r] = xp[((size_t)tn * Bb + g * 16 + bi + r) * G4 + n0[tau] + lr];

        f32x4 acc[2];
        #pragma unroll
        for (int tau = 0; tau < 2; ++tau) {
            f32x4 a{};
            #pragma unroll
            for (int r = 0; r < 4; ++r) a[r] = xc[tau][r];
            acc[tau] = a;
        }

        if (t > 0) {
            // wait for all 8 participants to finish step t-1 (2 increments each)
            unsigned int tgt = 2u * (unsigned int)t;
            if (l < 8) {
                const unsigned int* fp = flags + (g * 8 + l) * 32;
                while (__hip_atomic_load(fp, __ATOMIC_ACQUIRE, __HIP_MEMORY_SCOPE_AGENT) < tgt)
                    __builtin_amdgcn_s_sleep(1);
            }
            // A fragments: full h_{t-1} (16x256) via agent-scope 8B atomic loads
            const float* hrow = hexch + ((size_t)(g * Tt + (t - 1)) * 16 + lr) * 256;
            #pragma unroll
            for (int kt = 0; kt < 8; ++kt) {
                int koff = kt * 32 + lh * 8;
                union { unsigned long long u[4]; float f[8]; } cv;
                #pragma unroll
                for (int j = 0; j < 4; ++j)
                    cv.u[j] = __hip_atomic_load((const unsigned long long*)(hrow + koff + 2 * j),
                                                __ATOMIC_RELAXED, __HIP_MEMORY_SCOPE_AGENT);
                bf16x8 af;
                #pragma unroll
                for (int j = 0; j < 8; ++j) af[j] = (bf16)cv.f[j];
                #pragma unroll
                for (int tau = 0; tau < 2; ++tau)
                    acc[tau] = __builtin_amdgcn_mfma_f32_16x16x32_bf16(af, wf[tau][kt], acc[tau], 0, 0, 0);
            }
        }

        // exchange g,o accumulators to the i,f waves
        if (qsel == 1) {
            #pragma unroll
            for (int tau = 0; tau < 2; ++tau)
                #pragma unroll
                for (int r = 0; r < 4; ++r) zone[hsel][tau][l][r] = acc[tau][r];
        }
        __syncthreads();
        if (qsel == 0) {
            #pragma unroll
            for (int r = 0; r < 4; ++r) {
                float iv = acc[0][r], fv = acc[1][r];
                float gv = zone[hsel][0][l][r], ov = zone[hsel][1][l][r];
                float cn = sigm(fv) * cst[r] + sigm(iv) * tanh_(gv);
                cst[r] = cn;
                float hv = sigm(ov) * tanh_(cn);
                size_t addr = ((size_t)(g * Tt + t) * 16 + bi + r) * 256 + c * 32 + hsel * 16 + lr;
                __hip_atomic_store(hexch + addr, hv, __ATOMIC_RELAXED, __HIP_MEMORY_SCOPE_AGENT);
            }
            if (l == 0)
                __hip_atomic_fetch_add(selfflag, 1u, __ATOMIC_RELEASE, __HIP_MEMORY_SCOPE_AGENT);
        }
        __syncthreads();   // protect zone WAR for next step

        #pragma unroll
        for (int tau = 0; tau < 2; ++tau)
            #pragma unroll
            for (int r = 0; r < 4; ++r) xc[tau][r] = xn[tau][r];
    }
}

// ============================================================
// k_attn: one wave per (b,t). 9 dot products + att softmax, all f32.
// ============================================================
DEV float wred(float v) {
    #pragma unroll
    for (int off = 32; off > 0; off >>= 1) v += __shfl_down(v, off, 64);
    return v;
}

__global__ __launch_bounds__(256, 4)
void k_attn(const float* __restrict__ hexch, const float* __restrict__ ntr,
            const int* __restrict__ hidx,
            const float* __restrict__ a1w, const float* __restrict__ a1b,
            const float* __restrict__ a2w, const float* __restrict__ a2b,
            float* __restrict__ out)
{
    int wid = blockIdx.x * 4 + (threadIdx.x >> 6);
    if (wid >= Mm) return;
    int l = threadIdx.x & 63;
    int t = wid / Bb, b = wid % Bb;
    int g = b >> 4, bi = b & 15;

    float4 nt4 = *(const float4*)(ntr + (size_t)wid * 256 + l * 4);
    float4 w14 = *(const float4*)(a1w + l * 4);
    float4 w24 = *(const float4*)(a2w + l * 4);
    float lg[9], fh[9];
    float fn = nt4.x * w24.x + nt4.y * w24.y + nt4.z * w24.z + nt4.w * w24.w;
    #pragma unroll
    for (int k = 0; k < 9; ++k) {
        int ts = (k == 0) ? t : hidx[((size_t)b * Tt + t) * 8 + (k - 1)];
        const float* hrow = hexch + ((size_t)(g * Tt + ts) * 16 + bi) * 256;
        float4 h4 = *(const float4*)(hrow + l * 4);
        lg[k] = h4.x * nt4.x + h4.y * nt4.y + h4.z * nt4.z + h4.w * nt4.w;
        fh[k] = h4.x * w14.x + h4.y * w14.y + h4.z * w14.z + h4.w * w14.w;
    }
    #pragma unroll
    for (int k = 0; k < 9; ++k) { lg[k] = wred(lg[k]); fh[k] = wred(fh[k]); }
    fn = wred(fn);
    if (l == 0) {
        float f2 = fn + a2b[0], b1 = a1b[0];
        float tv[9], mx = -1e30f;
        #pragma unroll
        for (int k = 0; k < 9; ++k) { tv[k] = tanh_(fh[k] + b1 + f2); mx = fmaxf(mx, tv[k]); }
        float s = 0.f, accv = 0.f;
        #pragma unroll
        for (int k = 0; k < 9; ++k) { float e = __expf(tv[k] - mx); s += e; accv += e * lg[k]; }
        out[(size_t)b * Tt + t] = accv / s;   // output layout (B,T)
    }
}

// ============================================================
extern "C" void kernel_launch(void* const* d_in, const int* in_sizes, int n_in,
                              void* d_out, int out_size, void* d_ws, size_t ws_size,
                              hipStream_t stream)
{
    const float* q   = (const float*)d_in[0];
    const float* nq  = (const float*)d_in[1];
    const float* sk  = (const float*)d_in[2];   // skills
    const float* an  = (const float*)d_in[3];   // answers
    const int*   hid = (const int*)d_in[4];
    const float* Wnf = (const float*)d_in[5];
    const float* bnf = (const float*)d_in[6];
    const float* Wli = (const float*)d_in[7];
    const float* bli = (const float*)d_in[8];
    const float* Wih = (const float*)d_in[9];
    const float* Whh = (const float*)d_in[10];
    const float* bih = (const float*)d_in[11];
    const float* bhh = (const float*)d_in[12];
    const float* a1w = (const float*)d_in[13];
    const float* a1b = (const float*)d_in[14];
    const float* a2w = (const float*)d_in[15];
    const float* a2b = (const float*)d_in[16];
    float* out = (float*)d_out;

    char* ws = (char*)d_ws;   // NOTE: needs ~176 MiB (WS_NEED)
    unsigned int* flags = (unsigned int*)(ws + OFF_FLAGS);
    bf16* wli_h = (bf16*)(ws + OFF_WLI_H);
    bf16* wli_l = (bf16*)(ws + OFF_WLI_L);
    bf16* wih_h = (bf16*)(ws + OFF_WIH_H);
    bf16* wih_l = (bf16*)(ws + OFF_WIH_L);
    bf16* wnf_h = (bf16*)(ws + OFF_WNF_H);
    bf16* wnf_l = (bf16*)(ws + OFF_WNF_L);
    bf16* xin_h = (bf16*)(ws + OFF_XIN_H);
    bf16* xin_l = (bf16*)(ws + OFF_XIN_L);
    float* xp   = (float*)(ws + OFF_XP);
    float* hex  = (float*)(ws + OFF_HEX);
    float* ntr  = (float*)(ws + OFF_NTR);

    k_reset<<<8, 256, 0, stream>>>(flags);
    k_prep<<<512, 256, 0, stream>>>(Wli, Wih, Wnf, wli_h, wli_l, wih_h, wih_l, wnf_h, wnf_l);

    // x_in (hi/lo) = [q|ans|skill] @ W_li^T + b_li     (M x 256, K=768)
    dim3 g1(Tt, 2);
    k_gemm<0, 0, 768, 256><<<g1, 256, 0, stream>>>(q, an, sk, nullptr, nullptr,
        wli_h, wli_l, bli, nullptr, nullptr, xin_h, xin_l);

    // xp = x_in @ W_ih^T + (b_ih + b_hh)               (M x 1024, K=256), layout [t][b][g]
    dim3 g2(Tt, 8);
    k_gemm<2, 1, 256, 1024><<<g2, 256, 0, stream>>>(nullptr, nullptr, nullptr, xin_h, xin_l,
        wih_h, wih_l, bih, bhh, xp, nullptr, nullptr);

    // next_trans = relu(nq @ W_nf^T + b_nf)            (M x 256, K=256)
    dim3 g3(Tt, 2);
    k_gemm<1, 2, 256, 256><<<g3, 256, 0, stream>>>(nq, nullptr, nullptr, nullptr, nullptr,
        wnf_h, wnf_l, bnf, nullptr, ntr, nullptr, nullptr);

    k_lstm<<<64, 256, 0, stream>>>(Whh, xp, hex, flags);

    k_attn<<<Mm / 4, 256, 0, stream>>>(hex, ntr, hid, a1w, a1b, a2w, a2b, out);
    (void)in_sizes; (void)n_in; (void)out_size; (void)ws_size;
}

// Round 2
// 1283.291 us; speedup vs baseline: 1.4008x; 1.4008x over previous
//
#include <hip/hip_runtime.h>
#include <hip/hip_bf16.h>
#include <stdint.h>

#define DEV __device__ __forceinline__

typedef __bf16 bf16;
typedef __attribute__((ext_vector_type(8))) __bf16 bf16x8;
typedef __attribute__((ext_vector_type(4))) float f32x4;

constexpr int Bb = 128, Tt = 199, Ee = 256, Hh = 256;
constexpr int Mm = Bb * Tt;       // 25472 = 199 M-tiles of 128 exactly
constexpr int G4 = 4 * Hh;        // 1024 gates

// ---------------- workspace layout (bytes) ----------------
constexpr size_t OFF_FLAGS = 0;                                   // 64 flags @128B stride
constexpr size_t OFF_WLI_H = 8192;
constexpr size_t OFF_WLI_L = OFF_WLI_H + (size_t)Hh * 768 * 2;
constexpr size_t OFF_WIH_H = OFF_WLI_L + (size_t)Hh * 768 * 2;
constexpr size_t OFF_WIH_L = OFF_WIH_H + (size_t)G4 * Hh * 2;
constexpr size_t OFF_WNF_H = OFF_WIH_L + (size_t)G4 * Hh * 2;
constexpr size_t OFF_WNF_L = OFF_WNF_H + (size_t)Hh * Ee * 2;
constexpr size_t OFF_XIN_H = OFF_WNF_L + (size_t)Hh * Ee * 2;
constexpr size_t OFF_XIN_L = OFF_XIN_H + (size_t)Mm * Hh * 2;
constexpr size_t OFF_XP    = OFF_XIN_L + (size_t)Mm * Hh * 2;     // f32 [t][b][1024]
constexpr size_t OFF_HEX   = OFF_XP    + (size_t)Mm * G4 * 4;     // f32 [g][t][16][256]
constexpr size_t OFF_NTR   = OFF_HEX   + (size_t)Mm * Hh * 4;     // f32 [t*128+b][256]
constexpr size_t WS_NEED   = OFF_NTR   + (size_t)Mm * Hh * 4;     // ~176 MiB total

DEV float sigm(float x)  { return 1.0f / (1.0f + __expf(-x)); }
DEV float tanh_(float x) { return 2.0f / (1.0f + __expf(-2.0f * x)) - 1.0f; }

// ============================================================
// k_reset: zero the lstm sync flags (must run before k_lstm each call)
// ============================================================
__global__ void k_reset(unsigned int* flags) {
    int i = blockIdx.x * 256 + threadIdx.x;
    if (i < 64 * 32) flags[i] = 0;
}

// ============================================================
// k_prep: split weights into bf16 hi/lo pairs
// ============================================================
__global__ void k_prep(const float* __restrict__ Wli, const float* __restrict__ Wih,
                       const float* __restrict__ Wnf,
                       bf16* wli_h, bf16* wli_l, bf16* wih_h, bf16* wih_l,
                       bf16* wnf_h, bf16* wnf_l) {
    const int n1 = Hh * 768, n2 = G4 * Hh, n3 = Hh * Ee;
    for (int idx = blockIdx.x * 256 + threadIdx.x; idx < n1 + n2 + n3;
         idx += gridDim.x * 256) {
        const float* src; bf16 *dh, *dl; int j;
        if (idx < n1)           { src = Wli; dh = wli_h; dl = wli_l; j = idx; }
        else if (idx < n1 + n2) { src = Wih; dh = wih_h; dl = wih_l; j = idx - n1; }
        else                    { src = Wnf; dh = wnf_h; dl = wnf_l; j = idx - n1 - n2; }
        float x = src[j];
        bf16 h = (bf16)x;
        dh[j] = h;
        dl[j] = (bf16)(x - (float)h);
    }
}

// ============================================================
// k_gemm: split-bf16 (3-pass) 128x128x64-tile GEMM, 4 waves.
//   M index m = t*128 + b  (M=25472 = 199 tiles exactly, blockIdx.x = t)
//   AMODE: 0 = concat3 f32 (q|ans|skill), on-the-fly hi/lo split
//          1 = single f32 source, on-the-fly split
//          2 = pre-split bf16 pair
//   EPI:   0 = add bias0, store hi/lo bf16 pair
//          1 = add bias0+bias1, store f32
//          2 = add bias0, relu, store f32
// ============================================================
template<int AMODE, int EPI, int KT, int NTOT>
__global__ __launch_bounds__(256, 2)
void k_gemm(const float* __restrict__ a0, const float* __restrict__ a1,
            const float* __restrict__ a2,
            const bf16* __restrict__ ah_src, const bf16* __restrict__ al_src,
            const bf16* __restrict__ bh_src, const bf16* __restrict__ bl_src,
            const float* __restrict__ bias0, const float* __restrict__ bias1,
            float* __restrict__ outf, bf16* __restrict__ outh, bf16* __restrict__ outl)
{
    __shared__ __align__(16) bf16 lA[2][128 * 64];   // [hi/lo][row*64 + swz]
    __shared__ __align__(16) bf16 lB[2][128 * 64];
    const int tid = threadIdx.x;
    const int l = tid & 63, w = tid >> 6;
    const int wr = w >> 1, wc = w & 1;       // 2x2 wave grid, 64x64 per wave
    const int lr = l & 15, lh = l >> 4;
    const int mb = blockIdx.x;               // == t
    const int nb = blockIdx.y;

    f32x4 acc[4][4];
    #pragma unroll
    for (int i = 0; i < 4; ++i)
        #pragma unroll
        for (int j = 0; j < 4; ++j) acc[i][j] = {};

    for (int ks = 0; ks < KT / 64; ++ks) {
        // ---- stage A and B tiles (reg-staged, swizzled: granule ^ (row&7)) ----
        #pragma unroll
        for (int p = 0; p < 4; ++p) {
            int Gi = p * 256 + tid;            // 1024 granules of 8 elems
            int row = Gi >> 3, gsl = Gi & 7;
            int k = ks * 64 + gsl * 8;
            int dst = row * 64 + ((gsl ^ (row & 7)) * 8);
            // A
            if constexpr (AMODE == 2) {
                size_t base = (size_t)(mb * 128 + row) * KT + k;
                *(bf16x8*)&lA[0][dst] = *(const bf16x8*)(ah_src + base);
                *(bf16x8*)&lA[1][dst] = *(const bf16x8*)(al_src + base);
            } else {
                const float* src; int e;
                if constexpr (AMODE == 0) {
                    int seg = k >> 8; e = k & 255;
                    src = (seg == 0) ? a0 : (seg == 1) ? a1 : a2;
                } else { src = a0; e = k; }
                size_t base = ((size_t)row * Tt + mb) * Ee + e;  // [b][t][e]
                float4 v0 = *(const float4*)(src + base);
                float4 v1 = *(const float4*)(src + base + 4);
                float vv[8] = {v0.x, v0.y, v0.z, v0.w, v1.x, v1.y, v1.z, v1.w};
                bf16x8 hv, lv;
                #pragma unroll
                for (int j = 0; j < 8; ++j) {
                    bf16 h = (bf16)vv[j];
                    hv[j] = h;
                    lv[j] = (bf16)(vv[j] - (float)h);
                }
                *(bf16x8*)&lA[0][dst] = hv;
                *(bf16x8*)&lA[1][dst] = lv;
            }
            // B (weights, always pre-split)
            size_t bbase = (size_t)(nb * 128 + row) * KT + k;
            *(bf16x8*)&lB[0][dst] = *(const bf16x8*)(bh_src + bbase);
            *(bf16x8*)&lB[1][dst] = *(const bf16x8*)(bl_src + bbase);
        }
        __syncthreads();
        #pragma unroll
        for (int kt = 0; kt < 2; ++kt) {
            bf16x8 ah[4], al[4], bh[4], bl[4];
            #pragma unroll
            for (int mt = 0; mt < 4; ++mt) {
                int row = wr * 64 + mt * 16 + lr;
                int g = (kt * 4 + lh) ^ (row & 7);
                ah[mt] = *(const bf16x8*)&lA[0][row * 64 + g * 8];
                al[mt] = *(const bf16x8*)&lA[1][row * 64 + g * 8];
            }
            #pragma unroll
            for (int nt = 0; nt < 4; ++nt) {
                int row = wc * 64 + nt * 16 + lr;
                int g = (kt * 4 + lh) ^ (row & 7);
                bh[nt] = *(const bf16x8*)&lB[0][row * 64 + g * 8];
                bl[nt] = *(const bf16x8*)&lB[1][row * 64 + g * 8];
            }
            #pragma unroll
            for (int mt = 0; mt < 4; ++mt)
                #pragma unroll
                for (int nt = 0; nt < 4; ++nt) {
                    acc[mt][nt] = __builtin_amdgcn_mfma_f32_16x16x32_bf16(ah[mt], bh[nt], acc[mt][nt], 0, 0, 0);
                    acc[mt][nt] = __builtin_amdgcn_mfma_f32_16x16x32_bf16(ah[mt], bl[nt], acc[mt][nt], 0, 0, 0);
                    acc[mt][nt] = __builtin_amdgcn_mfma_f32_16x16x32_bf16(al[mt], bh[nt], acc[mt][nt], 0, 0, 0);
                }
        }
        __syncthreads();
    }
    // ---- epilogue: D layout col = l&15 (n), row = (l>>4)*4 + r (m) ----
    #pragma unroll
    for (int nt = 0; nt < 4; ++nt) {
        int n = nb * 128 + wc * 64 + nt * 16 + lr;
        float bv = bias0[n];
        if constexpr (EPI == 1) bv += bias1[n];
        #pragma unroll
        for (int mt = 0; mt < 4; ++mt)
            #pragma unroll
            for (int r = 0; r < 4; ++r) {
                int m = mb * 128 + wr * 64 + mt * 16 + lh * 4 + r;
                float v = acc[mt][nt][r] + bv;
                if constexpr (EPI == 0) {
                    bf16 h = (bf16)v;
                    outh[(size_t)m * NTOT + n] = h;
                    outl[(size_t)m * NTOT + n] = (bf16)(v - (float)h);
                } else if constexpr (EPI == 1) {
                    outf[(size_t)m * NTOT + n] = v;
                } else {
                    outf[(size_t)m * NTOT + n] = fmaxf(v, 0.f);
                }
            }
    }
}

// ============================================================
// k_lstm: 8 batch-groups x 8 participant WGs (grid=64, 256 thr = 4 waves).
// Participant c owns 32 hidden units -> 128 gate rows; W_hh fragments live
// in VGPRs. ALL cross-WG communication is RELAXED agent-scope atomics
// (sc1, cache-bypassing) -- no acquire/release, so no buffer_inv/buffer_wbl2
// cache-maintenance storms. Writer ordering: h-stores -> s_waitcnt vmcnt(0)
// -> relaxed flag add. Reader: relaxed poll (control-dep) -> relaxed h loads.
// XCD mapping: g = blk&7 so each group's participants + xp stream share an XCD.
// ============================================================
__global__ __launch_bounds__(256, 1)
void k_lstm(const float* __restrict__ Whh, const float* __restrict__ xp,
            float* __restrict__ hexch, unsigned int* __restrict__ flags)
{
    const int tid = threadIdx.x;
    const int l = tid & 63, w = tid >> 6;
    const int g = blockIdx.x & 7, c = blockIdx.x >> 3;
    const int qsel = w & 1, hsel = w >> 1;
    const int lr = l & 15, lh = l >> 4;
    const int bi = lh * 4;                      // local batch base for regs

    __shared__ float zone[2][2][64][4];         // [hsel][tau(g,o)][lane][reg]

    // ---- hoist W_hh fragments into VGPRs (B-operand: col = l&15 = gate row) ----
    bf16x8 wf[2][8];
    int n0[2];
    #pragma unroll
    for (int tau = 0; tau < 2; ++tau) {
        n0[tau] = (qsel * 2 + tau) * 256 + c * 32 + hsel * 16;
        #pragma unroll
        for (int kt = 0; kt < 8; ++kt) {
            size_t base = (size_t)(n0[tau] + lr) * Hh + kt * 32 + lh * 8;
            float4 v0 = *(const float4*)(Whh + base);
            float4 v1 = *(const float4*)(Whh + base + 4);
            float vv[8] = {v0.x, v0.y, v0.z, v0.w, v1.x, v1.y, v1.z, v1.w};
            #pragma unroll
            for (int j = 0; j < 8; ++j) wf[tau][kt][j] = (bf16)vv[j];
        }
    }

    float xc[2][4], xn[2][4];
    #pragma unroll
    for (int tau = 0; tau < 2; ++tau)
        #pragma unroll
        for (int r = 0; r < 4; ++r)
            xc[tau][r] = xp[((size_t)0 * Bb + g * 16 + bi + r) * G4 + n0[tau] + lr];

    float cst[4] = {0.f, 0.f, 0.f, 0.f};
    unsigned int* selfflag = flags + (g * 8 + c) * 32;

    for (int t = 0; t < Tt; ++t) {
        // prefetch xp for t+1 (independent of sync)
        int tn = (t + 1 < Tt) ? t + 1 : t;
        #pragma unroll
        for (int tau = 0; tau < 2; ++tau)
            #pragma unroll
            for (int r = 0; r < 4; ++r)
                xn[tau][r] = xp[((size_t)tn * Bb + g * 16 + bi + r) * G4 + n0[tau] + lr];

        f32x4 acc[2];
        #pragma unroll
        for (int tau = 0; tau < 2; ++tau) {
            f32x4 a{};
            #pragma unroll
            for (int r = 0; r < 4; ++r) a[r] = xc[tau][r];
            acc[tau] = a;
        }

        if (t > 0) {
            // wait for all 8 participants to finish step t-1 (2 increments each)
            // RELAXED poll: no buffer_inv per iteration.
            unsigned int tgt = 2u * (unsigned int)t;
            if (l < 8) {
                const unsigned int* fp = flags + (g * 8 + l) * 32;
                while (__hip_atomic_load(fp, __ATOMIC_RELAXED, __HIP_MEMORY_SCOPE_AGENT) < tgt)
                    __builtin_amdgcn_s_sleep(1);
            }
            // A fragments: full h_{t-1} (16x256) via agent-scope 8B relaxed loads
            const float* hrow = hexch + ((size_t)(g * Tt + (t - 1)) * 16 + lr) * 256;
            #pragma unroll
            for (int kt = 0; kt < 8; ++kt) {
                int koff = kt * 32 + lh * 8;
                union { unsigned long long u[4]; float f[8]; } cv;
                #pragma unroll
                for (int j = 0; j < 4; ++j)
                    cv.u[j] = __hip_atomic_load((const unsigned long long*)(hrow + koff + 2 * j),
                                                __ATOMIC_RELAXED, __HIP_MEMORY_SCOPE_AGENT);
                bf16x8 af;
                #pragma unroll
                for (int j = 0; j < 8; ++j) af[j] = (bf16)cv.f[j];
                #pragma unroll
                for (int tau = 0; tau < 2; ++tau)
                    acc[tau] = __builtin_amdgcn_mfma_f32_16x16x32_bf16(af, wf[tau][kt], acc[tau], 0, 0, 0);
            }
        }

        // exchange g,o accumulators to the i,f waves
        if (qsel == 1) {
            #pragma unroll
            for (int tau = 0; tau < 2; ++tau)
                #pragma unroll
                for (int r = 0; r < 4; ++r) zone[hsel][tau][l][r] = acc[tau][r];
        }
        __syncthreads();
        if (qsel == 0) {
            #pragma unroll
            for (int r = 0; r < 4; ++r) {
                float iv = acc[0][r], fv = acc[1][r];
                float gv = zone[hsel][0][l][r], ov = zone[hsel][1][l][r];
                float cn = sigm(fv) * cst[r] + sigm(iv) * tanh_(gv);
                cst[r] = cn;
                float hv = sigm(ov) * tanh_(cn);
                size_t addr = ((size_t)(g * Tt + t) * 16 + bi + r) * 256 + c * 32 + hsel * 16 + lr;
                __hip_atomic_store(hexch + addr, hv, __ATOMIC_RELAXED, __HIP_MEMORY_SCOPE_AGENT);
            }
            // drain this wave's sc1 h-stores to the coherence point, THEN
            // publish with a RELAXED add (no buffer_wbl2).
            asm volatile("s_waitcnt vmcnt(0)" ::: "memory");
            if (l == 0)
                __hip_atomic_fetch_add(selfflag, 1u, __ATOMIC_RELAXED, __HIP_MEMORY_SCOPE_AGENT);
        }
        __syncthreads();   // protect zone WAR for next step

        #pragma unroll
        for (int tau = 0; tau < 2; ++tau)
            #pragma unroll
            for (int r = 0; r < 4; ++r) xc[tau][r] = xn[tau][r];
    }
}

// ============================================================
// k_attn: one wave per (b,t). 9 dot products + att softmax, all f32.
// ============================================================
DEV float wred(float v) {
    #pragma unroll
    for (int off = 32; off > 0; off >>= 1) v += __shfl_down(v, off, 64);
    return v;
}

__global__ __launch_bounds__(256, 4)
void k_attn(const float* __restrict__ hexch, const float* __restrict__ ntr,
            const int* __restrict__ hidx,
            const float* __restrict__ a1w, const float* __restrict__ a1b,
            const float* __restrict__ a2w, const float* __restrict__ a2b,
            float* __restrict__ out)
{
    int wid = blockIdx.x * 4 + (threadIdx.x >> 6);
    if (wid >= Mm) return;
    int l = threadIdx.x & 63;
    int t = wid / Bb, b = wid % Bb;
    int g = b >> 4, bi = b & 15;

    float4 nt4 = *(const float4*)(ntr + (size_t)wid * 256 + l * 4);
    float4 w14 = *(const float4*)(a1w + l * 4);
    float4 w24 = *(const float4*)(a2w + l * 4);
    float lg[9], fh[9];
    float fn = nt4.x * w24.x + nt4.y * w24.y + nt4.z * w24.z + nt4.w * w24.w;
    #pragma unroll
    for (int k = 0; k < 9; ++k) {
        int ts = (k == 0) ? t : hidx[((size_t)b * Tt + t) * 8 + (k - 1)];
        const float* hrow = hexch + ((size_t)(g * Tt + ts) * 16 + bi) * 256;
        float4 h4 = *(const float4*)(hrow + l * 4);
        lg[k] = h4.x * nt4.x + h4.y * nt4.y + h4.z * nt4.z + h4.w * nt4.w;
        fh[k] = h4.x * w14.x + h4.y * w14.y + h4.z * w14.z + h4.w * w14.w;
    }
    #pragma unroll
    for (int k = 0; k < 9; ++k) { lg[k] = wred(lg[k]); fh[k] = wred(fh[k]); }
    fn = wred(fn);
    if (l == 0) {
        float f2 = fn + a2b[0], b1 = a1b[0];
        float tv[9], mx = -1e30f;
        #pragma unroll
        for (int k = 0; k < 9; ++k) { tv[k] = tanh_(fh[k] + b1 + f2); mx = fmaxf(mx, tv[k]); }
        float s = 0.f, accv = 0.f;
        #pragma unroll
        for (int k = 0; k < 9; ++k) { float e = __expf(tv[k] - mx); s += e; accv += e * lg[k]; }
        out[(size_t)b * Tt + t] = accv / s;   // output layout (B,T)
    }
}

// ============================================================
extern "C" void kernel_launch(void* const* d_in, const int* in_sizes, int n_in,
                              void* d_out, int out_size, void* d_ws, size_t ws_size,
                              hipStream_t stream)
{
    const float* q   = (const float*)d_in[0];
    const float* nq  = (const float*)d_in[1];
    const float* sk  = (const float*)d_in[2];   // skills
    const float* an  = (const float*)d_in[3];   // answers
    const int*   hid = (const int*)d_in[4];
    const float* Wnf = (const float*)d_in[5];
    const float* bnf = (const float*)d_in[6];
    const float* Wli = (const float*)d_in[7];
    const float* bli = (const float*)d_in[8];
    const float* Wih = (const float*)d_in[9];
    const float* Whh = (const float*)d_in[10];
    const float* bih = (const float*)d_in[11];
    const float* bhh = (const float*)d_in[12];
    const float* a1w = (const float*)d_in[13];
    const float* a1b = (const float*)d_in[14];
    const float* a2w = (const float*)d_in[15];
    const float* a2b = (const float*)d_in[16];
    float* out = (float*)d_out;

    char* ws = (char*)d_ws;   // NOTE: needs ~176 MiB (WS_NEED)
    unsigned int* flags = (unsigned int*)(ws + OFF_FLAGS);
    bf16* wli_h = (bf16*)(ws + OFF_WLI_H);
    bf16* wli_l = (bf16*)(ws + OFF_WLI_L);
    bf16* wih_h = (bf16*)(ws + OFF_WIH_H);
    bf16* wih_l = (bf16*)(ws + OFF_WIH_L);
    bf16* wnf_h = (bf16*)(ws + OFF_WNF_H);
    bf16* wnf_l = (bf16*)(ws + OFF_WNF_L);
    bf16* xin_h = (bf16*)(ws + OFF_XIN_H);
    bf16* xin_l = (bf16*)(ws + OFF_XIN_L);
    float* xp   = (float*)(ws + OFF_XP);
    float* hex  = (float*)(ws + OFF_HEX);
    float* ntr  = (float*)(ws + OFF_NTR);

    k_reset<<<8, 256, 0, stream>>>(flags);
    k_prep<<<512, 256, 0, stream>>>(Wli, Wih, Wnf, wli_h, wli_l, wih_h, wih_l, wnf_h, wnf_l);

    // x_in (hi/lo) = [q|ans|skill] @ W_li^T + b_li     (M x 256, K=768)
    dim3 g1(Tt, 2);
    k_gemm<0, 0, 768, 256><<<g1, 256, 0, stream>>>(q, an, sk, nullptr, nullptr,
        wli_h, wli_l, bli, nullptr, nullptr, xin_h, xin_l);

    // xp = x_in @ W_ih^T + (b_ih + b_hh)               (M x 1024, K=256), layout [t][b][g]
    dim3 g2(Tt, 8);
    k_gemm<2, 1, 256, 1024><<<g2, 256, 0, stream>>>(nullptr, nullptr, nullptr, xin_h, xin_l,
        wih_h, wih_l, bih, bhh, xp, nullptr, nullptr);

    // next_trans = relu(nq @ W_nf^T + b_nf)            (M x 256, K=256)
    dim3 g3(Tt, 2);
    k_gemm<1, 2, 256, 256><<<g3, 256, 0, stream>>>(nq, nullptr, nullptr, nullptr, nullptr,
        wnf_h, wnf_l, bnf, nullptr, ntr, nullptr, nullptr);

    k_lstm<<<64, 256, 0, stream>>>(Whh, xp, hex, flags);

    k_attn<<<Mm / 4, 256, 0, stream>>>(hex, ntr, hid, a1w, a1b, a2w, a2b, out);
    (void)in_sizes; (void)n_in; (void)out_size; (void)ws_size;
}